// Round 1
// baseline (365.369 us; speedup 1.0000x reference)
//
#include <hip/hip_runtime.h>

#define Bb 4
#define Tt 64
#define Nn 16
#define Mm 8
#define Dd 512
#define RR 32      // Bb*Mm rows per (t,n) block
#define QSTR 520   // padded LDS row stride in u16 (breaks 1024B bank stride)

typedef __attribute__((ext_vector_type(8))) short bf16x8;
typedef __attribute__((ext_vector_type(4))) float f32x4;

__device__ __forceinline__ unsigned short f2bf(float f) {
    union { float f; unsigned int u; } v; v.f = f;
    unsigned int r = (v.u + 0x7fffu + ((v.u >> 16) & 1u)) >> 16;  // RNE
    return (unsigned short)r;
}
__device__ __forceinline__ float bf2f(unsigned short h) {
    union { unsigned int u; float f; } v; v.u = ((unsigned int)h) << 16;
    return v.f;
}

// Pack Wq|Wk|Wv (each [512,512] f32, rows = output feature e) into bf16 Wb[1536][512].
__global__ __launch_bounds__(256) void convert_w_kernel(
    const float* __restrict__ Wq, const float* __restrict__ Wk,
    const float* __restrict__ Wv, unsigned short* __restrict__ Wb)
{
    int idx = blockIdx.x * 256 + threadIdx.x;   // float4 units; 196608 total
    int flat = idx << 2;
    int row = flat >> 9;        // 0..1535
    int d = flat & 511;
    const float* src = (row < 512) ? Wq : ((row < 1024) ? Wk : Wv);
    int r = row & 511;
    float4 v = *(const float4*)(src + r * Dd + d);
    ushort4 o;
    o.x = f2bf(v.x); o.y = f2bf(v.y); o.z = f2bf(v.z); o.w = f2bf(v.w);
    *(ushort4*)(Wb + row * Dd + d) = o;
}

// One block per (t, n). 512 threads = 8 waves.
__global__ __launch_bounds__(512, 2) void fused_attn_kernel(
    const float* __restrict__ x, const unsigned short* __restrict__ Wb,
    const float* __restrict__ bq, const float* __restrict__ bk,
    const float* __restrict__ bv, float* __restrict__ out)
{
    __shared__ unsigned short lds_x[RR * QSTR];        // 33,280 B  (x_tn bf16)
    __shared__ unsigned short lds_qkv[3 * RR * QSTR];  // 99,840 B  (Q,K,V bf16)
    __shared__ float lds_p[Mm * Mm];                   // scores -> probs

    const int tid = threadIdx.x;
    const int t = blockIdx.x >> 4;
    const int n = blockIdx.x & 15;

    // ---- Phase 1: stage x rows (b,m) -> bf16 LDS, coalesced float4 loads ----
    #pragma unroll
    for (int i = 0; i < 8; ++i) {
        int fi = i * 512 + tid;      // float4 index, 4096 total
        int flat = fi << 2;
        int row = flat >> 9;         // 0..31  (= b*8 + m)
        int d = flat & 511;
        int b = row >> 3, m = row & 7;
        float4 v = *(const float4*)(x + ((((long)(b * Tt + t)) * Nn + n) * Mm + m) * Dd + d);
        ushort4 o;
        o.x = f2bf(v.x); o.y = f2bf(v.y); o.z = f2bf(v.z); o.w = f2bf(v.w);
        *(ushort4*)(&lds_x[row * QSTR + d]) = o;
    }
    __syncthreads();

    // ---- Phase 2: QKV = x @ W^T + bias via mfma_f32_16x16x32_bf16 ----
    // A[m=lane&15][k=quad*8+j], B[n=lane&15][k=quad*8+j], D: row=quad*4+r, col=lane&15
    const int lane = tid & 63;
    const int wave = tid >> 6;
    const int lcol = lane & 15;
    const int quad = lane >> 4;

    bf16x8 a0[16], a1[16];   // A fragments for both 16-row m-tiles, all 16 K-steps
    #pragma unroll
    for (int kk = 0; kk < 16; ++kk) {
        a0[kk] = *(const bf16x8*)(&lds_x[lcol * QSTR + kk * 32 + quad * 8]);
        a1[kk] = *(const bf16x8*)(&lds_x[(16 + lcol) * QSTR + kk * 32 + quad * 8]);
    }

    // 96 e-tiles of 16 features (0..511 Q, 512..1023 K, 1024..1535 V); 12 per wave.
    for (int et = 0; et < 12; ++et) {
        int ebase = (wave * 12 + et) * 16;
        const unsigned short* wp = Wb + (long)(ebase + lcol) * Dd + quad * 8;
        f32x4 acc0 = {0.f, 0.f, 0.f, 0.f}, acc1 = {0.f, 0.f, 0.f, 0.f};
        #pragma unroll
        for (int kk = 0; kk < 16; ++kk) {
            bf16x8 bf = *(const bf16x8*)(wp + kk * 32);
            acc0 = __builtin_amdgcn_mfma_f32_16x16x32_bf16(a0[kk], bf, acc0, 0, 0, 0);
            acc1 = __builtin_amdgcn_mfma_f32_16x16x32_bf16(a1[kk], bf, acc1, 0, 0, 0);
        }
        int ecol = ebase + lcol;          // 0..1535
        int proj = ecol >> 9;             // 0=Q 1=K 2=V (tiles never cross projections)
        int f = ecol & 511;
        const float* bp = (proj == 0) ? bq : ((proj == 1) ? bk : bv);
        float bias = bp[f];
        unsigned short* qbase = &lds_qkv[(proj * RR) * QSTR + f];
        #pragma unroll
        for (int r = 0; r < 4; ++r) {
            int mrow = quad * 4 + r;
            qbase[mrow * QSTR]        = f2bf(acc0[r] + bias);
            qbase[(16 + mrow) * QSTR] = f2bf(acc1[r] + bias);
        }
    }
    __syncthreads();

    // ---- Phase 3: scores S[m][k] = scale * sum_{b,d} Q[b*8+m][d]*K[b*8+k][d] ----
    {
        int p = tid >> 3;          // 0..63 -> (m,k)
        int j = tid & 7;           // 8 threads per pair, 64-d stripes
        int sm = p >> 3;
        int sk = p & 7;
        float part = 0.f;
        for (int b4 = 0; b4 < 4; ++b4) {
            const unsigned short* qr = &lds_qkv[(0 * RR + b4 * 8 + sm) * QSTR + j * 64];
            const unsigned short* kr = &lds_qkv[(1 * RR + b4 * 8 + sk) * QSTR + j * 64];
            #pragma unroll
            for (int i = 0; i < 16; ++i) {
                ushort4 qa = *(const ushort4*)(qr + i * 4);
                ushort4 ka = *(const ushort4*)(kr + i * 4);
                part += bf2f(qa.x) * bf2f(ka.x) + bf2f(qa.y) * bf2f(ka.y)
                      + bf2f(qa.z) * bf2f(ka.z) + bf2f(qa.w) * bf2f(ka.w);
            }
        }
        part += __shfl_xor(part, 1);
        part += __shfl_xor(part, 2);
        part += __shfl_xor(part, 4);
        if (j == 0) lds_p[sm * Mm + sk] = part * 0.04419417382415922f;  // 1/sqrt(512)
    }
    __syncthreads();

    // ---- Phase 4: softmax over k (8 values) per m ----
    if (tid < 8) {
        int m = tid;
        float mx = lds_p[m * Mm + 0];
        #pragma unroll
        for (int k = 1; k < 8; ++k) mx = fmaxf(mx, lds_p[m * Mm + k]);
        float e[8]; float sum = 0.f;
        #pragma unroll
        for (int k = 0; k < 8; ++k) { e[k] = __expf(lds_p[m * Mm + k] - mx); sum += e[k]; }
        float inv = 1.f / sum;
        #pragma unroll
        for (int k = 0; k < 8; ++k) lds_p[m * Mm + k] = e[k] * inv;
    }
    __syncthreads();

    // ---- Phase 5: out[b,m,d] = sum_k P[m][k] * V[b*8+k][d], coalesced stores ----
    {
        int d = tid;               // 0..511
        for (int r = 0; r < RR; ++r) {
            int b = r >> 3, m = r & 7;
            float acc = 0.f;
            #pragma unroll
            for (int k = 0; k < 8; ++k)
                acc += lds_p[m * Mm + k] * bf2f(lds_qkv[(2 * RR + b * 8 + k) * QSTR + d]);
            out[((((long)(b * Tt + t)) * Nn + n) * Mm + m) * Dd + d] = acc;
        }
    }
}

extern "C" void kernel_launch(void* const* d_in, const int* in_sizes, int n_in,
                              void* d_out, int out_size, void* d_ws, size_t ws_size,
                              hipStream_t stream) {
    const float* x  = (const float*)d_in[0];
    const float* Wq = (const float*)d_in[1];
    const float* bq = (const float*)d_in[2];
    const float* Wk = (const float*)d_in[3];
    const float* bk = (const float*)d_in[4];
    const float* Wv = (const float*)d_in[5];
    const float* bv = (const float*)d_in[6];
    float* out = (float*)d_out;
    unsigned short* Wb = (unsigned short*)d_ws;   // 1536*512*2 = 1.5 MiB

    convert_w_kernel<<<768, 256, 0, stream>>>(Wq, Wk, Wv, Wb);
    fused_attn_kernel<<<Tt * Nn, 512, 0, stream>>>(x, Wb, bq, bk, bv, out);
}

// Round 2
// 316.453 us; speedup vs baseline: 1.1546x; 1.1546x over previous
//
#include <hip/hip_runtime.h>

#define Bb 4
#define Tt 64
#define Nn 16
#define Mm 8
#define Dd 512
#define RR 32      // Bb*Mm rows per (t,n) block
#define QSTR 520   // padded LDS row stride in u16 (260 dwords == 4 mod 32 -> 2-way max on frag reads)

typedef __attribute__((ext_vector_type(8))) short bf16x8;
typedef __attribute__((ext_vector_type(4))) float f32x4;

__device__ __forceinline__ unsigned short f2bf(float f) {
    union { float f; unsigned int u; } v; v.f = f;
    unsigned int r = (v.u + 0x7fffu + ((v.u >> 16) & 1u)) >> 16;  // RNE
    return (unsigned short)r;
}
__device__ __forceinline__ float bf2f(unsigned short h) {
    union { unsigned int u; float f; } v; v.u = ((unsigned int)h) << 16;
    return v.f;
}

// Pack Wq|Wk|Wv (each [512,512] f32, rows = output feature e) into bf16 Wb[1536][512].
__global__ __launch_bounds__(256) void convert_w_kernel(
    const float* __restrict__ Wq, const float* __restrict__ Wk,
    const float* __restrict__ Wv, unsigned short* __restrict__ Wb)
{
    int idx = blockIdx.x * 256 + threadIdx.x;   // float4 units; 196608 total
    int flat = idx << 2;
    int row = flat >> 9;        // 0..1535
    int d = flat & 511;
    const float* src = (row < 512) ? Wq : ((row < 1024) ? Wk : Wv);
    int r = row & 511;
    float4 v = *(const float4*)(src + r * Dd + d);
    ushort4 o;
    o.x = f2bf(v.x); o.y = f2bf(v.y); o.z = f2bf(v.z); o.w = f2bf(v.w);
    *(ushort4*)(Wb + row * Dd + d) = o;
}

// One block per (t, n). 512 threads = 8 waves.
__global__ __launch_bounds__(512, 2) void fused_attn_kernel(
    const float* __restrict__ x, const unsigned short* __restrict__ Wb,
    const float* __restrict__ bq, const float* __restrict__ bk,
    const float* __restrict__ bv, float* __restrict__ out)
{
    __shared__ unsigned short lds_x[RR * QSTR];        // 33,280 B  (x_tn bf16)
    __shared__ unsigned short lds_qkv[3 * RR * QSTR];  // 99,840 B  (Q,K,V bf16)
    __shared__ float lds_p[Mm * Mm];                   // scores -> probs

    const int tid = threadIdx.x;
    const int t = blockIdx.x >> 4;
    const int n = blockIdx.x & 15;

    // ---- Phase 1: stage x rows (b,m) -> bf16 LDS, coalesced float4 loads ----
    #pragma unroll
    for (int i = 0; i < 8; ++i) {
        int fi = i * 512 + tid;      // float4 index, 4096 total
        int flat = fi << 2;
        int row = flat >> 9;         // 0..31  (= b*8 + m)
        int d = flat & 511;
        int b = row >> 3, m = row & 7;
        float4 v = *(const float4*)(x + ((((long)(b * Tt + t)) * Nn + n) * Mm + m) * Dd + d);
        ushort4 o;
        o.x = f2bf(v.x); o.y = f2bf(v.y); o.z = f2bf(v.z); o.w = f2bf(v.w);
        *(ushort4*)(&lds_x[row * QSTR + d]) = o;
    }
    __syncthreads();

    // ---- Phase 2: QKV = x @ W^T + bias via mfma_f32_16x16x32_bf16 ----
    // A[m=lane&15][k=quad*8+j], B[n=lane&15][k=quad*8+j], D: row=quad*4+r, col=lane&15
    const int lane = tid & 63;
    const int wave = tid >> 6;
    const int lcol = lane & 15;
    const int quad = lane >> 4;

    // A fragments for both 16-row m-tiles, all 16 K-steps — keep register-resident.
    bf16x8 a0[16], a1[16];
    #pragma unroll
    for (int kk = 0; kk < 16; ++kk) {
        a0[kk] = *(const bf16x8*)(&lds_x[lcol * QSTR + kk * 32 + quad * 8]);
        a1[kk] = *(const bf16x8*)(&lds_x[(16 + lcol) * QSTR + kk * 32 + quad * 8]);
    }

    // 96 e-tiles of 16 features (0..511 Q, 512..1023 K, 1024..1535 V); 12 per wave.
    for (int et = 0; et < 12; ++et) {
        int ebase = (wave * 12 + et) * 16;
        const unsigned short* wp = Wb + (long)(ebase + lcol) * Dd + quad * 8;

        // Batch-issue all 16 B-fragment loads (independent) -> vmcnt-pipelined.
        bf16x8 bf[16];
        #pragma unroll
        for (int kk = 0; kk < 16; ++kk) bf[kk] = *(const bf16x8*)(wp + kk * 32);

        f32x4 acc0 = {0.f, 0.f, 0.f, 0.f}, acc1 = {0.f, 0.f, 0.f, 0.f};
        #pragma unroll
        for (int kk = 0; kk < 16; ++kk) {
            acc0 = __builtin_amdgcn_mfma_f32_16x16x32_bf16(a0[kk], bf[kk], acc0, 0, 0, 0);
            acc1 = __builtin_amdgcn_mfma_f32_16x16x32_bf16(a1[kk], bf[kk], acc1, 0, 0, 0);
        }

        int ecol = ebase + lcol;          // 0..1535
        int proj = ecol >> 9;             // 0=Q 1=K 2=V (tiles never cross projections)
        int f = ecol & 511;
        const float* bp = (proj == 0) ? bq : ((proj == 1) ? bk : bv);
        float bias = bp[f];
        unsigned short* qbase = &lds_qkv[(proj * RR) * QSTR + f];
        #pragma unroll
        for (int r = 0; r < 4; ++r) {
            int mrow = quad * 4 + r;
            qbase[mrow * QSTR]        = f2bf(acc0[r] + bias);
            qbase[(16 + mrow) * QSTR] = f2bf(acc1[r] + bias);
        }
    }
    __syncthreads();

    // ---- Phase 3: scores S[m][k] = scale * sum_{b,d} Q[b*8+m][d]*K[b*8+k][d] ----
    // 64 pairs x 8 threads; interleaved ushort4 stripes: Q reads broadcast, K <=2-3 way.
    {
        int p = tid >> 3;          // 0..63 -> (m,k)
        int j = tid & 7;
        int sm = p >> 3;
        int sk = p & 7;
        float part = 0.f;
        for (int b4 = 0; b4 < 4; ++b4) {
            const unsigned short* qr = &lds_qkv[(0 * RR + b4 * 8 + sm) * QSTR];
            const unsigned short* kr = &lds_qkv[(1 * RR + b4 * 8 + sk) * QSTR];
            #pragma unroll
            for (int i = 0; i < 16; ++i) {
                int off = (j + i * 8) * 4;          // j*4 + i*32 u16
                ushort4 qa = *(const ushort4*)(qr + off);
                ushort4 ka = *(const ushort4*)(kr + off);
                part += bf2f(qa.x) * bf2f(ka.x) + bf2f(qa.y) * bf2f(ka.y)
                      + bf2f(qa.z) * bf2f(ka.z) + bf2f(qa.w) * bf2f(ka.w);
            }
        }
        part += __shfl_xor(part, 1);
        part += __shfl_xor(part, 2);
        part += __shfl_xor(part, 4);
        if (j == 0) lds_p[sm * Mm + sk] = part * 0.04419417382415922f;  // 1/sqrt(512)
    }
    __syncthreads();

    // ---- Phase 4: softmax over k (8 values) per m ----
    if (tid < 8) {
        int m = tid;
        float mx = lds_p[m * Mm + 0];
        #pragma unroll
        for (int k = 1; k < 8; ++k) mx = fmaxf(mx, lds_p[m * Mm + k]);
        float e[8]; float sum = 0.f;
        #pragma unroll
        for (int k = 0; k < 8; ++k) { e[k] = __expf(lds_p[m * Mm + k] - mx); sum += e[k]; }
        float inv = 1.f / sum;
        #pragma unroll
        for (int k = 0; k < 8; ++k) lds_p[m * Mm + k] = e[k] * inv;
    }
    __syncthreads();

    // ---- Phase 5: out[b,m,d] = sum_k P[m][k] * V[b*8+k][d] — vectorized ----
    {
        int d4 = tid & 127;        // float4 group: d = d4*4
        int b = tid >> 7;          // 0..3
        #pragma unroll
        for (int m = 0; m < 8; ++m) {
            float4 o = {0.f, 0.f, 0.f, 0.f};
            #pragma unroll
            for (int k = 0; k < 8; ++k) {
                float pw = lds_p[m * Mm + k];
                ushort4 v = *(const ushort4*)(&lds_qkv[(2 * RR + b * 8 + k) * QSTR + d4 * 4]);
                o.x += pw * bf2f(v.x);
                o.y += pw * bf2f(v.y);
                o.z += pw * bf2f(v.z);
                o.w += pw * bf2f(v.w);
            }
            *(float4*)(out + ((((long)(b * Tt + t)) * Nn + n) * Mm + m) * Dd + d4 * 4) = o;
        }
    }
}

extern "C" void kernel_launch(void* const* d_in, const int* in_sizes, int n_in,
                              void* d_out, int out_size, void* d_ws, size_t ws_size,
                              hipStream_t stream) {
    const float* x  = (const float*)d_in[0];
    const float* Wq = (const float*)d_in[1];
    const float* bq = (const float*)d_in[2];
    const float* Wk = (const float*)d_in[3];
    const float* bk = (const float*)d_in[4];
    const float* Wv = (const float*)d_in[5];
    const float* bv = (const float*)d_in[6];
    float* out = (float*)d_out;
    unsigned short* Wb = (unsigned short*)d_ws;   // 1536*512*2 = 1.5 MiB

    convert_w_kernel<<<768, 256, 0, stream>>>(Wq, Wk, Wv, Wb);
    fused_attn_kernel<<<Tt * Nn, 512, 0, stream>>>(x, Wb, bq, bk, bv, out);
}

// Round 3
// 311.471 us; speedup vs baseline: 1.1730x; 1.0160x over previous
//
#include <hip/hip_runtime.h>

#define Bb 4
#define Tt 64
#define Nn 16
#define Mm 8
#define Dd 512
#define RR 32      // Bb*Mm rows per (t,n) block
#define QSTR 520   // padded LDS row stride in u16

typedef __attribute__((ext_vector_type(8))) short bf16x8;
typedef __attribute__((ext_vector_type(4))) float f32x4;

__device__ __forceinline__ unsigned short f2bf(float f) {
    union { float f; unsigned int u; } v; v.f = f;
    unsigned int r = (v.u + 0x7fffu + ((v.u >> 16) & 1u)) >> 16;  // RNE
    return (unsigned short)r;
}
__device__ __forceinline__ float bf2f(unsigned short h) {
    union { unsigned int u; float f; } v; v.u = ((unsigned int)h) << 16;
    return v.f;
}

// Pack Wq|Wk|Wv (each [512,512] f32, rows = output feature e) into bf16 Wb[1536][512].
__global__ __launch_bounds__(256) void convert_w_kernel(
    const float* __restrict__ Wq, const float* __restrict__ Wk,
    const float* __restrict__ Wv, unsigned short* __restrict__ Wb)
{
    int idx = blockIdx.x * 256 + threadIdx.x;   // float4 units; 196608 total
    int flat = idx << 2;
    int row = flat >> 9;        // 0..1535
    int d = flat & 511;
    const float* src = (row < 512) ? Wq : ((row < 1024) ? Wk : Wv);
    int r = row & 511;
    float4 v = *(const float4*)(src + r * Dd + d);
    ushort4 o;
    o.x = f2bf(v.x); o.y = f2bf(v.y); o.z = f2bf(v.z); o.w = f2bf(v.w);
    *(ushort4*)(Wb + row * Dd + d) = o;
}

// One block per (t, n). 1024 threads = 16 waves (4 waves/SIMD for latency hiding).
__global__ __launch_bounds__(1024, 4) void fused_attn_kernel(
    const float* __restrict__ x, const unsigned short* __restrict__ Wb,
    const float* __restrict__ bq, const float* __restrict__ bk,
    const float* __restrict__ bv, float* __restrict__ out)
{
    __shared__ unsigned short lds_x[RR * QSTR];        // 33,280 B  (x_tn bf16)
    __shared__ unsigned short lds_qkv[3 * RR * QSTR];  // 99,840 B  (Q,K,V bf16)
    __shared__ float lds_p[Mm * Mm];                   // scores -> probs

    const int tid = threadIdx.x;
    const int t = blockIdx.x >> 4;
    const int n = blockIdx.x & 15;

    // ---- Phase 1: stage x rows (b,m) -> bf16 LDS, coalesced float4 loads ----
    #pragma unroll
    for (int i = 0; i < 4; ++i) {
        int fi = i * 1024 + tid;     // float4 index, 4096 total
        int flat = fi << 2;
        int row = flat >> 9;         // 0..31  (= b*8 + m)
        int d = flat & 511;
        int b = row >> 3, m = row & 7;
        float4 v = *(const float4*)(x + ((((long)(b * Tt + t)) * Nn + n) * Mm + m) * Dd + d);
        ushort4 o;
        o.x = f2bf(v.x); o.y = f2bf(v.y); o.z = f2bf(v.z); o.w = f2bf(v.w);
        *(ushort4*)(&lds_x[row * QSTR + d]) = o;
    }
    __syncthreads();

    // ---- Phase 2: QKV = x @ W^T + bias via mfma_f32_16x16x32_bf16 ----
    // A[m=lane&15][k=quad*8+j], B[n=lane&15][k=quad*8+j], D: row=quad*4+r, col=lane&15
    const int lane = tid & 63;
    const int wave = tid >> 6;       // 0..15
    const int lcol = lane & 15;
    const int quad = lane >> 4;

    // 96 e-tiles of 16 features; 6 per wave, processed as 3 pairs (shared A-reads).
    #pragma unroll
    for (int pr = 0; pr < 3; ++pr) {
        int e0 = wave * 6 + pr * 2;      // even tile; pair never straddles projection
        const unsigned short* wp0 = Wb + (long)(e0 * 16 + lcol) * Dd + quad * 8;
        const unsigned short* wp1 = wp0 + 16 * Dd;

        // depth-4 circular prefetch of B fragments (<=8 loads outstanding)
        bf16x8 pb[4][2];
        #pragma unroll
        for (int i = 0; i < 4; ++i) {
            pb[i][0] = *(const bf16x8*)(wp0 + i * 32);
            pb[i][1] = *(const bf16x8*)(wp1 + i * 32);
        }

        f32x4 acc00 = {0.f,0.f,0.f,0.f}, acc10 = {0.f,0.f,0.f,0.f};
        f32x4 acc01 = {0.f,0.f,0.f,0.f}, acc11 = {0.f,0.f,0.f,0.f};

        #pragma unroll
        for (int kk = 0; kk < 16; ++kk) {
            bf16x8 b0 = pb[kk & 3][0];
            bf16x8 b1 = pb[kk & 3][1];
            if (kk < 12) {
                pb[kk & 3][0] = *(const bf16x8*)(wp0 + (kk + 4) * 32);
                pb[kk & 3][1] = *(const bf16x8*)(wp1 + (kk + 4) * 32);
            }
            bf16x8 a0 = *(const bf16x8*)(&lds_x[lcol * QSTR + kk * 32 + quad * 8]);
            bf16x8 a1 = *(const bf16x8*)(&lds_x[(16 + lcol) * QSTR + kk * 32 + quad * 8]);
            acc00 = __builtin_amdgcn_mfma_f32_16x16x32_bf16(a0, b0, acc00, 0, 0, 0);
            acc10 = __builtin_amdgcn_mfma_f32_16x16x32_bf16(a1, b0, acc10, 0, 0, 0);
            acc01 = __builtin_amdgcn_mfma_f32_16x16x32_bf16(a0, b1, acc01, 0, 0, 0);
            acc11 = __builtin_amdgcn_mfma_f32_16x16x32_bf16(a1, b1, acc11, 0, 0, 0);
        }

        // epilogue for both tiles of the pair
        #pragma unroll
        for (int tt = 0; tt < 2; ++tt) {
            int ecol = (e0 + tt) * 16 + lcol;   // 0..1535
            int proj = ecol >> 9;               // 0=Q 1=K 2=V
            int f = ecol & 511;
            const float* bp = (proj == 0) ? bq : ((proj == 1) ? bk : bv);
            float bias = bp[f];
            unsigned short* qbase = &lds_qkv[(proj * RR) * QSTR + f];
            f32x4 aa0 = tt ? acc01 : acc00;
            f32x4 aa1 = tt ? acc11 : acc10;
            #pragma unroll
            for (int r = 0; r < 4; ++r) {
                int mrow = quad * 4 + r;
                qbase[mrow * QSTR]        = f2bf(aa0[r] + bias);
                qbase[(16 + mrow) * QSTR] = f2bf(aa1[r] + bias);
            }
        }
    }
    __syncthreads();

    // ---- Phase 3: scores S[m][k] = scale * sum_{b,d} Q[b*8+m][d]*K[b*8+k][d] ----
    // 64 pairs x 16 threads; interleaved ushort4 stripes.
    {
        int p = tid >> 4;          // 0..63 -> (m,k)
        int j = tid & 15;
        int sm = p >> 3;
        int sk = p & 7;
        float part = 0.f;
        #pragma unroll
        for (int b4 = 0; b4 < 4; ++b4) {
            const unsigned short* qr = &lds_qkv[(0 * RR + b4 * 8 + sm) * QSTR];
            const unsigned short* kr = &lds_qkv[(1 * RR + b4 * 8 + sk) * QSTR];
            #pragma unroll
            for (int i = 0; i < 8; ++i) {
                int off = (j + i * 16) * 4;          // covers 0..511 in ushort4 units
                ushort4 qa = *(const ushort4*)(qr + off);
                ushort4 ka = *(const ushort4*)(kr + off);
                part += bf2f(qa.x) * bf2f(ka.x) + bf2f(qa.y) * bf2f(ka.y)
                      + bf2f(qa.z) * bf2f(ka.z) + bf2f(qa.w) * bf2f(ka.w);
            }
        }
        part += __shfl_xor(part, 1);
        part += __shfl_xor(part, 2);
        part += __shfl_xor(part, 4);
        part += __shfl_xor(part, 8);
        if (j == 0) lds_p[p] = part * 0.04419417382415922f;  // 1/sqrt(512)
    }
    __syncthreads();

    // ---- Phase 4: softmax over k (8 values) per m — 64 threads + shfl ----
    if (tid < 64) {
        int p = tid;               // m = p>>3, k = p&7 ; groups of 8 lanes aligned
        float s = lds_p[p];
        float mx = s;
        mx = fmaxf(mx, __shfl_xor(mx, 1));
        mx = fmaxf(mx, __shfl_xor(mx, 2));
        mx = fmaxf(mx, __shfl_xor(mx, 4));
        float e = __expf(s - mx);
        float sum = e;
        sum += __shfl_xor(sum, 1);
        sum += __shfl_xor(sum, 2);
        sum += __shfl_xor(sum, 4);
        lds_p[p] = e / sum;
    }
    __syncthreads();

    // ---- Phase 5: out[b,m,d] = sum_k P[m][k] * V[b*8+k][d] — vectorized ----
    {
        int d4 = tid & 127;        // float4 group: d = d4*4
        int b = (tid >> 7) & 3;    // 0..3
        int mh = tid >> 9;         // 0..1 -> m in [mh*4, mh*4+4)
        float4 vv[8];
        float pw[2][8];
        #pragma unroll
        for (int k = 0; k < 8; ++k) {
            ushort4 v = *(const ushort4*)(&lds_qkv[(2 * RR + b * 8 + k) * QSTR + d4 * 4]);
            vv[k].x = bf2f(v.x); vv[k].y = bf2f(v.y);
            vv[k].z = bf2f(v.z); vv[k].w = bf2f(v.w);
        }
        #pragma unroll
        for (int mi = 0; mi < 4; ++mi) {
            int m = mh * 4 + mi;
            float4 o = {0.f, 0.f, 0.f, 0.f};
            #pragma unroll
            for (int k = 0; k < 8; ++k) {
                float w = lds_p[m * Mm + k];
                o.x += w * vv[k].x;
                o.y += w * vv[k].y;
                o.z += w * vv[k].z;
                o.w += w * vv[k].w;
            }
            *(float4*)(out + ((((long)(b * Tt + t)) * Nn + n) * Mm + m) * Dd + d4 * 4) = o;
        }
    }
}

extern "C" void kernel_launch(void* const* d_in, const int* in_sizes, int n_in,
                              void* d_out, int out_size, void* d_ws, size_t ws_size,
                              hipStream_t stream) {
    const float* x  = (const float*)d_in[0];
    const float* Wq = (const float*)d_in[1];
    const float* bq = (const float*)d_in[2];
    const float* Wk = (const float*)d_in[3];
    const float* bk = (const float*)d_in[4];
    const float* Wv = (const float*)d_in[5];
    const float* bv = (const float*)d_in[6];
    float* out = (float*)d_out;
    unsigned short* Wb = (unsigned short*)d_ws;   // 1536*512*2 = 1.5 MiB

    convert_w_kernel<<<768, 256, 0, stream>>>(Wq, Wk, Wv, Wb);
    fused_attn_kernel<<<Tt * Nn, 1024, 0, stream>>>(x, Wb, bq, bk, bv, out);
}

// Round 4
// 200.315 us; speedup vs baseline: 1.8240x; 1.5549x over previous
//
#include <hip/hip_runtime.h>

#define Bb 4
#define Tt 64
#define Nn 16
#define Mm 8
#define Dd 512
#define RR 32      // Bb*Mm rows per (t,n) block
#define QSTR 520   // padded LDS row stride in u16

typedef __attribute__((ext_vector_type(8))) short bf16x8;
typedef __attribute__((ext_vector_type(4))) float f32x4;

__device__ __forceinline__ unsigned short f2bf(float f) {
    union { float f; unsigned int u; } v; v.f = f;
    unsigned int r = (v.u + 0x7fffu + ((v.u >> 16) & 1u)) >> 16;  // RNE
    return (unsigned short)r;
}
__device__ __forceinline__ float bf2f(unsigned short h) {
    union { unsigned int u; float f; } v; v.u = ((unsigned int)h) << 16;
    return v.f;
}

// Pack Wq|Wk|Wv (f32 [512,512] each, rows = output feature) into bf16 in MFMA
// FRAGMENT ORDER: Wb[((e*16 + kk)*64 + lane)*8 + j] = W[e*16 + (lane&15)][kk*32 + (lane>>4)*8 + j]
// so phase-2's per-(tile,kk) wave load is lane-contiguous (1024 B coalesced).
__global__ __launch_bounds__(256) void convert_w_kernel(
    const float* __restrict__ Wq, const float* __restrict__ Wk,
    const float* __restrict__ Wv, unsigned short* __restrict__ Wb)
{
    int idx = blockIdx.x * 256 + threadIdx.x;   // ushort4 units; 196608 total
    int flat = idx << 2;
    int row = flat >> 9;        // 0..1535
    int d = flat & 511;
    const float* src = (row < 512) ? Wq : ((row < 1024) ? Wk : Wv);
    int r = row & 511;
    float4 v = *(const float4*)(src + r * Dd + d);   // coalesced read
    ushort4 o;
    o.x = f2bf(v.x); o.y = f2bf(v.y); o.z = f2bf(v.z); o.w = f2bf(v.w);
    int e = row >> 4, lcol = row & 15;
    int kk = d >> 5, quad = (d >> 3) & 3, j = d & 7;  // j in {0,4}
    *(ushort4*)(Wb + ((((e * 16 + kk) * 64) + quad * 16 + lcol) << 3) + j) = o;
}

// One block per (t, n). 1024 threads = 16 waves (4 waves/SIMD).
__global__ __launch_bounds__(1024, 4) void fused_attn_kernel(
    const float* __restrict__ x, const unsigned short* __restrict__ Wb,
    const float* __restrict__ bq, const float* __restrict__ bk,
    const float* __restrict__ bv, float* __restrict__ out)
{
    __shared__ unsigned short lds_x[RR * QSTR];        // 33,280 B  (x_tn bf16)
    __shared__ unsigned short lds_qkv[3 * RR * QSTR];  // 99,840 B  (Q,K,V bf16)
    __shared__ float lds_p[Mm * Mm];                   // scores -> probs

    const int tid = threadIdx.x;
    const int t = blockIdx.x >> 4;
    const int n = blockIdx.x & 15;

    // ---- Phase 1: stage x rows (b,m) -> bf16 LDS, coalesced float4 loads ----
    #pragma unroll
    for (int i = 0; i < 4; ++i) {
        int fi = i * 1024 + tid;     // float4 index, 4096 total
        int flat = fi << 2;
        int row = flat >> 9;         // 0..31  (= b*8 + m)
        int d = flat & 511;
        int b = row >> 3, m = row & 7;
        float4 v = *(const float4*)(x + ((((long)(b * Tt + t)) * Nn + n) * Mm + m) * Dd + d);
        ushort4 o;
        o.x = f2bf(v.x); o.y = f2bf(v.y); o.z = f2bf(v.z); o.w = f2bf(v.w);
        *(ushort4*)(&lds_x[row * QSTR + d]) = o;
    }
    __syncthreads();

    // ---- Phase 2: QKV = x @ W^T + bias via mfma_f32_16x16x32_bf16 ----
    // A[m=lane&15][k=quad*8+j], B[n=lane&15][k=quad*8+j], D: row=quad*4+r, col=lane&15
    const int lane = tid & 63;
    const int wave = tid >> 6;       // 0..15
    const int lcol = lane & 15;
    const int quad = lane >> 4;

    // 96 e-tiles of 16 features; 6 per wave, processed as 3 pairs (shared A-reads).
    #pragma unroll
    for (int pr = 0; pr < 3; ++pr) {
        int e0 = wave * 6 + pr * 2;      // even tile; pair never straddles projection
        // Fragment-order W: tile stride = 16*64*8 = 8192 u16; kk stride = 512 u16.
        const unsigned short* wp0 = Wb + ((long)e0 * 8192) + lane * 8;
        const unsigned short* wp1 = wp0 + 8192;

        // depth-4 circular prefetch of B fragments (<=8 loads outstanding)
        bf16x8 pb[4][2];
        #pragma unroll
        for (int i = 0; i < 4; ++i) {
            pb[i][0] = *(const bf16x8*)(wp0 + i * 512);
            pb[i][1] = *(const bf16x8*)(wp1 + i * 512);
        }

        f32x4 acc00 = {0.f,0.f,0.f,0.f}, acc10 = {0.f,0.f,0.f,0.f};
        f32x4 acc01 = {0.f,0.f,0.f,0.f}, acc11 = {0.f,0.f,0.f,0.f};

        #pragma unroll
        for (int kk = 0; kk < 16; ++kk) {
            bf16x8 b0 = pb[kk & 3][0];
            bf16x8 b1 = pb[kk & 3][1];
            if (kk < 12) {
                pb[kk & 3][0] = *(const bf16x8*)(wp0 + (kk + 4) * 512);
                pb[kk & 3][1] = *(const bf16x8*)(wp1 + (kk + 4) * 512);
            }
            bf16x8 a0 = *(const bf16x8*)(&lds_x[lcol * QSTR + kk * 32 + quad * 8]);
            bf16x8 a1 = *(const bf16x8*)(&lds_x[(16 + lcol) * QSTR + kk * 32 + quad * 8]);
            acc00 = __builtin_amdgcn_mfma_f32_16x16x32_bf16(a0, b0, acc00, 0, 0, 0);
            acc10 = __builtin_amdgcn_mfma_f32_16x16x32_bf16(a1, b0, acc10, 0, 0, 0);
            acc01 = __builtin_amdgcn_mfma_f32_16x16x32_bf16(a0, b1, acc01, 0, 0, 0);
            acc11 = __builtin_amdgcn_mfma_f32_16x16x32_bf16(a1, b1, acc11, 0, 0, 0);
        }

        // epilogue for both tiles of the pair
        #pragma unroll
        for (int tt = 0; tt < 2; ++tt) {
            int ecol = (e0 + tt) * 16 + lcol;   // 0..1535
            int proj = ecol >> 9;               // 0=Q 1=K 2=V
            int f = ecol & 511;
            const float* bp = (proj == 0) ? bq : ((proj == 1) ? bk : bv);
            float bias = bp[f];
            unsigned short* qbase = &lds_qkv[(proj * RR) * QSTR + f];
            f32x4 aa0 = tt ? acc01 : acc00;
            f32x4 aa1 = tt ? acc11 : acc10;
            #pragma unroll
            for (int r = 0; r < 4; ++r) {
                int mrow = quad * 4 + r;
                qbase[mrow * QSTR]        = f2bf(aa0[r] + bias);
                qbase[(16 + mrow) * QSTR] = f2bf(aa1[r] + bias);
            }
        }
    }
    __syncthreads();

    // ---- Phase 3: scores S[m][k] = scale * sum_{b,d} Q[b*8+m][d]*K[b*8+k][d] ----
    // 64 pairs x 16 threads; interleaved ushort4 stripes.
    {
        int p = tid >> 4;          // 0..63 -> (m,k)
        int j = tid & 15;
        int sm = p >> 3;
        int sk = p & 7;
        float part = 0.f;
        #pragma unroll
        for (int b4 = 0; b4 < 4; ++b4) {
            const unsigned short* qr = &lds_qkv[(0 * RR + b4 * 8 + sm) * QSTR];
            const unsigned short* kr = &lds_qkv[(1 * RR + b4 * 8 + sk) * QSTR];
            #pragma unroll
            for (int i = 0; i < 8; ++i) {
                int off = (j + i * 16) * 4;          // covers 0..511 in ushort4 units
                ushort4 qa = *(const ushort4*)(qr + off);
                ushort4 ka = *(const ushort4*)(kr + off);
                part += bf2f(qa.x) * bf2f(ka.x) + bf2f(qa.y) * bf2f(ka.y)
                      + bf2f(qa.z) * bf2f(ka.z) + bf2f(qa.w) * bf2f(ka.w);
            }
        }
        part += __shfl_xor(part, 1);
        part += __shfl_xor(part, 2);
        part += __shfl_xor(part, 4);
        part += __shfl_xor(part, 8);
        if (j == 0) lds_p[p] = part * 0.04419417382415922f;  // 1/sqrt(512)
    }
    __syncthreads();

    // ---- Phase 4: softmax over k (8 values) per m — 64 threads + shfl ----
    if (tid < 64) {
        int p = tid;               // m = p>>3, k = p&7 ; groups of 8 lanes aligned
        float s = lds_p[p];
        float mx = s;
        mx = fmaxf(mx, __shfl_xor(mx, 1));
        mx = fmaxf(mx, __shfl_xor(mx, 2));
        mx = fmaxf(mx, __shfl_xor(mx, 4));
        float e = __expf(s - mx);
        float sum = e;
        sum += __shfl_xor(sum, 1);
        sum += __shfl_xor(sum, 2);
        sum += __shfl_xor(sum, 4);
        lds_p[p] = e / sum;
    }
    __syncthreads();

    // ---- Phase 5: out[b,m,d] = sum_k P[m][k] * V[b*8+k][d] — vectorized ----
    {
        int d4 = tid & 127;        // float4 group: d = d4*4
        int b = (tid >> 7) & 3;    // 0..3
        int mh = tid >> 9;         // 0..1 -> m in [mh*4, mh*4+4)
        float4 vv[8];
        #pragma unroll
        for (int k = 0; k < 8; ++k) {
            ushort4 v = *(const ushort4*)(&lds_qkv[(2 * RR + b * 8 + k) * QSTR + d4 * 4]);
            vv[k].x = bf2f(v.x); vv[k].y = bf2f(v.y);
            vv[k].z = bf2f(v.z); vv[k].w = bf2f(v.w);
        }
        #pragma unroll
        for (int mi = 0; mi < 4; ++mi) {
            int m = mh * 4 + mi;
            float4 o = {0.f, 0.f, 0.f, 0.f};
            #pragma unroll
            for (int k = 0; k < 8; ++k) {
                float w = lds_p[m * Mm + k];
                o.x += w * vv[k].x;
                o.y += w * vv[k].y;
                o.z += w * vv[k].z;
                o.w += w * vv[k].w;
            }
            *(float4*)(out + ((((long)(b * Tt + t)) * Nn + n) * Mm + m) * Dd + d4 * 4) = o;
        }
    }
}

extern "C" void kernel_launch(void* const* d_in, const int* in_sizes, int n_in,
                              void* d_out, int out_size, void* d_ws, size_t ws_size,
                              hipStream_t stream) {
    const float* x  = (const float*)d_in[0];
    const float* Wq = (const float*)d_in[1];
    const float* bq = (const float*)d_in[2];
    const float* Wk = (const float*)d_in[3];
    const float* bk = (const float*)d_in[4];
    const float* Wv = (const float*)d_in[5];
    const float* bv = (const float*)d_in[6];
    float* out = (float*)d_out;
    unsigned short* Wb = (unsigned short*)d_ws;   // 1536*512*2 = 1.5 MiB (fragment order)

    convert_w_kernel<<<768, 256, 0, stream>>>(Wq, Wk, Wv, Wb);
    fused_attn_kernel<<<Tt * Nn, 1024, 0, stream>>>(x, Wb, bq, bk, bv, out);
}

// Round 5
// 198.522 us; speedup vs baseline: 1.8404x; 1.0090x over previous
//
#include <hip/hip_runtime.h>

#define Bb 4
#define Tt 64
#define Nn 16
#define Mm 8
#define Dd 512
#define RR 32      // Bb*Mm rows per (t,n) block
#define QSTR 520   // padded LDS row stride in u16 (1040 B: 16B-aligned, breaks pow2)

typedef __attribute__((ext_vector_type(8))) short bf16x8;
typedef __attribute__((ext_vector_type(16))) float f32x16;

__device__ __forceinline__ unsigned short f2bf(float f) {
    union { float f; unsigned int u; } v; v.f = f;
    unsigned int r = (v.u + 0x7fffu + ((v.u >> 16) & 1u)) >> 16;  // RNE
    return (unsigned short)r;
}
__device__ __forceinline__ float bf2f(unsigned short h) {
    union { unsigned int u; float f; } v; v.u = ((unsigned int)h) << 16;
    return v.f;
}

// Pack Wq|Wk|Wv (f32 [512,512], rows = output feature) into bf16 in 32x32 MFMA
// fragment order: Wb[((e*32+kk)*64 + hi*32 + n)*8 + j] = W[e*32+n][kk*16 + hi*8 + j]
// (e in [0,48): 0-15=Q,16-31=K,32-47=V; per-(e,kk) wave load is lane-contiguous 1KB)
__global__ __launch_bounds__(256) void convert_w_kernel(
    const float* __restrict__ Wq, const float* __restrict__ Wk,
    const float* __restrict__ Wv, unsigned short* __restrict__ Wb)
{
    int idx = blockIdx.x * 256 + threadIdx.x;   // ushort4 units; 196608 total
    int flat = idx << 2;
    int row = flat >> 9;        // 0..1535
    int d = flat & 511;
    const float* src = (row < 512) ? Wq : ((row < 1024) ? Wk : Wv);
    int r = row & 511;
    float4 v = *(const float4*)(src + r * Dd + d);   // coalesced read
    ushort4 o;
    o.x = f2bf(v.x); o.y = f2bf(v.y); o.z = f2bf(v.z); o.w = f2bf(v.w);
    int e = row >> 5, n = row & 31;
    int kk = d >> 4, hi = (d >> 3) & 1, j = d & 7;   // j in {0,4}
    *(ushort4*)(Wb + ((((e * 32 + kk) * 64) + hi * 32 + n) << 3) + j) = o;
}

// One block per (t, n). 1024 threads = 16 waves (4 waves/SIMD).
__global__ __launch_bounds__(1024, 4) void fused_attn_kernel(
    const float* __restrict__ x, const unsigned short* __restrict__ Wb,
    const float* __restrict__ bq, const float* __restrict__ bk,
    const float* __restrict__ bv, float* __restrict__ out)
{
    __shared__ unsigned short lds_x[RR * QSTR];        // 33,280 B  (x_tn bf16)
    __shared__ unsigned short lds_qkv[3 * RR * QSTR];  // 99,840 B  (Q,K,V bf16)
    __shared__ float lds_p[Mm * Mm];                   // scores -> probs

    const int tid = threadIdx.x;
    const int t = blockIdx.x >> 4;
    const int n = blockIdx.x & 15;

    // ---- Phase 1: stage x rows (b,m) -> bf16 LDS, coalesced float4 loads ----
    #pragma unroll
    for (int i = 0; i < 4; ++i) {
        int fi = i * 1024 + tid;     // float4 index, 4096 total
        int flat = fi << 2;
        int row = flat >> 9;         // 0..31  (= b*8 + m)
        int d = flat & 511;
        int b = row >> 3, m = row & 7;
        float4 v = *(const float4*)(x + ((((long)(b * Tt + t)) * Nn + n) * Mm + m) * Dd + d);
        ushort4 o;
        o.x = f2bf(v.x); o.y = f2bf(v.y); o.z = f2bf(v.z); o.w = f2bf(v.w);
        *(ushort4*)(&lds_x[row * QSTR + d]) = o;
    }
    __syncthreads();

    // ---- Phase 2: QKV = x @ W^T + bias via mfma_f32_32x32x16_bf16 ----
    // A[row=lane&31][k=(lane>>5)*8+j]; B[col=lane&31][k=(lane>>5)*8+j];
    // D: col=lane&31, row=(reg&3)+8*(reg>>2)+4*(lane>>5)   (m74/m101-verified map)
    const int lane = tid & 63;
    const int wave = tid >> 6;       // 0..15
    const int arow = lane & 31;
    const int ahalf = lane >> 5;     // 0/1 -> k-offset 0/8

    {
        const int e0 = wave * 3;     // 3 feature-tiles (32 features each) per wave
        // Fragment-order W: tile stride = 32*64*8 = 16384 u16; kk stride = 512 u16.
        const unsigned short* wp0 = Wb + (long)e0 * 16384 + lane * 8;
        const unsigned short* wp1 = wp0 + 16384;
        const unsigned short* wp2 = wp1 + 16384;

        // depth-2 ping-pong prefetch of B fragments (<=6 loads outstanding)
        bf16x8 pb[2][3];
        #pragma unroll
        for (int i = 0; i < 2; ++i) {
            pb[i][0] = *(const bf16x8*)(wp0 + i * 512);
            pb[i][1] = *(const bf16x8*)(wp1 + i * 512);
            pb[i][2] = *(const bf16x8*)(wp2 + i * 512);
        }

        f32x16 acc0 = {0.f}, acc1 = {0.f}, acc2 = {0.f};
        #pragma unroll
        for (int r = 0; r < 16; ++r) { acc0[r] = 0.f; acc1[r] = 0.f; acc2[r] = 0.f; }

        const unsigned short* abase = &lds_x[arow * QSTR + ahalf * 8];

        #pragma unroll
        for (int kk = 0; kk < 32; ++kk) {
            int cur = kk & 1;
            bf16x8 b0 = pb[cur][0];
            bf16x8 b1 = pb[cur][1];
            bf16x8 b2 = pb[cur][2];
            if (kk < 30) {
                pb[cur][0] = *(const bf16x8*)(wp0 + (kk + 2) * 512);
                pb[cur][1] = *(const bf16x8*)(wp1 + (kk + 2) * 512);
                pb[cur][2] = *(const bf16x8*)(wp2 + (kk + 2) * 512);
            }
            bf16x8 a = *(const bf16x8*)(abase + kk * 16);   // one A-read feeds 3 MFMAs
            acc0 = __builtin_amdgcn_mfma_f32_32x32x16_bf16(a, b0, acc0, 0, 0, 0);
            acc1 = __builtin_amdgcn_mfma_f32_32x32x16_bf16(a, b1, acc1, 0, 0, 0);
            acc2 = __builtin_amdgcn_mfma_f32_32x32x16_bf16(a, b2, acc2, 0, 0, 0);
        }

        // epilogue: 3 tiles x 16 values/lane -> bf16 LDS (+bias)
        #pragma unroll
        for (int s = 0; s < 3; ++s) {
            f32x16 acc = (s == 0) ? acc0 : ((s == 1) ? acc1 : acc2);
            int ecol = (e0 + s) * 32 + arow;    // 0..1535
            int proj = ecol >> 9;               // 0=Q 1=K 2=V (tiles never straddle)
            int f = ecol & 511;
            const float* bp = (proj == 0) ? bq : ((proj == 1) ? bk : bv);
            float bias = bp[f];
            unsigned short* qbase = &lds_qkv[(proj * RR) * QSTR + f];
            #pragma unroll
            for (int r = 0; r < 16; ++r) {
                int mrow = (r & 3) + 8 * (r >> 2) + 4 * ahalf;
                qbase[mrow * QSTR] = f2bf(acc[r] + bias);
            }
        }
    }
    __syncthreads();

    // ---- Phase 3: scores S[m][k] = scale * sum_{b,d} Q[b*8+m][d]*K[b*8+k][d] ----
    // 64 pairs x 16 threads; interleaved ushort4 stripes.
    {
        int p = tid >> 4;          // 0..63 -> (m,k)
        int j = tid & 15;
        int sm = p >> 3;
        int sk = p & 7;
        float part = 0.f;
        #pragma unroll
        for (int b4 = 0; b4 < 4; ++b4) {
            const unsigned short* qr = &lds_qkv[(0 * RR + b4 * 8 + sm) * QSTR];
            const unsigned short* kr = &lds_qkv[(1 * RR + b4 * 8 + sk) * QSTR];
            #pragma unroll
            for (int i = 0; i < 8; ++i) {
                int off = (j + i * 16) * 4;          // covers 0..511 in ushort4 units
                ushort4 qa = *(const ushort4*)(qr + off);
                ushort4 ka = *(const ushort4*)(kr + off);
                part += bf2f(qa.x) * bf2f(ka.x) + bf2f(qa.y) * bf2f(ka.y)
                      + bf2f(qa.z) * bf2f(ka.z) + bf2f(qa.w) * bf2f(ka.w);
            }
        }
        part += __shfl_xor(part, 1);
        part += __shfl_xor(part, 2);
        part += __shfl_xor(part, 4);
        part += __shfl_xor(part, 8);
        if (j == 0) lds_p[p] = part * 0.04419417382415922f;  // 1/sqrt(512)
    }
    __syncthreads();

    // ---- Phase 4: softmax over k (8 values) per m — 64 threads + shfl ----
    if (tid < 64) {
        int p = tid;               // m = p>>3, k = p&7 ; groups of 8 lanes aligned
        float s = lds_p[p];
        float mx = s;
        mx = fmaxf(mx, __shfl_xor(mx, 1));
        mx = fmaxf(mx, __shfl_xor(mx, 2));
        mx = fmaxf(mx, __shfl_xor(mx, 4));
        float e = __expf(s - mx);
        float sum = e;
        sum += __shfl_xor(sum, 1);
        sum += __shfl_xor(sum, 2);
        sum += __shfl_xor(sum, 4);
        lds_p[p] = e / sum;
    }
    __syncthreads();

    // ---- Phase 5: out[b,m,d] = sum_k P[m][k] * V[b*8+k][d] — vectorized ----
    {
        int d4 = tid & 127;        // float4 group: d = d4*4
        int b = (tid >> 7) & 3;    // 0..3
        int mh = tid >> 9;         // 0..1 -> m in [mh*4, mh*4+4)
        float4 vv[8];
        #pragma unroll
        for (int k = 0; k < 8; ++k) {
            ushort4 v = *(const ushort4*)(&lds_qkv[(2 * RR + b * 8 + k) * QSTR + d4 * 4]);
            vv[k].x = bf2f(v.x); vv[k].y = bf2f(v.y);
            vv[k].z = bf2f(v.z); vv[k].w = bf2f(v.w);
        }
        #pragma unroll
        for (int mi = 0; mi < 4; ++mi) {
            int m = mh * 4 + mi;
            float4 o = {0.f, 0.f, 0.f, 0.f};
            #pragma unroll
            for (int k = 0; k < 8; ++k) {
                float w = lds_p[m * Mm + k];
                o.x += w * vv[k].x;
                o.y += w * vv[k].y;
                o.z += w * vv[k].z;
                o.w += w * vv[k].w;
            }
            *(float4*)(out + ((((long)(b * Tt + t)) * Nn + n) * Mm + m) * Dd + d4 * 4) = o;
        }
    }
}

extern "C" void kernel_launch(void* const* d_in, const int* in_sizes, int n_in,
                              void* d_out, int out_size, void* d_ws, size_t ws_size,
                              hipStream_t stream) {
    const float* x  = (const float*)d_in[0];
    const float* Wq = (const float*)d_in[1];
    const float* bq = (const float*)d_in[2];
    const float* Wk = (const float*)d_in[3];
    const float* bk = (const float*)d_in[4];
    const float* Wv = (const float*)d_in[5];
    const float* bv = (const float*)d_in[6];
    float* out = (float*)d_out;
    unsigned short* Wb = (unsigned short*)d_ws;   // 1.5 MiB, 32x32 fragment order

    convert_w_kernel<<<768, 256, 0, stream>>>(Wq, Wk, Wv, Wb);
    fused_attn_kernel<<<Tt * Nn, 1024, 0, stream>>>(x, Wb, bq, bk, bv, out);
}